// Round 7
// baseline (759.029 us; speedup 1.0000x reference)
//
#include <hip/hip_runtime.h>
#include <stdint.h>

#define T_TOK 8192
#define DDIM 1024
#define NEXP 8
#define HDIM 3072

typedef __attribute__((ext_vector_type(8))) short bfrag;   // 8 bf16 in 4 VGPRs
typedef __attribute__((ext_vector_type(4))) float facc;    // 4 fp32 acc

// async global->LDS, 16B per lane; LDS dest must be wave-uniform base (+lane*16)
__device__ __forceinline__ void gload16(const void* g, void* l) {
  __builtin_amdgcn_global_load_lds(
      (const __attribute__((address_space(1))) void*)g,
      (__attribute__((address_space(3))) void*)l, 16, 0, 0);
}

__device__ __forceinline__ unsigned short f2bf(float f) {
  unsigned int u = __float_as_uint(f);
  u += 0x7FFFu + ((u >> 16) & 1u);      // round-to-nearest-even
  return (unsigned short)(u >> 16);
}

// ------------- prefix sum of counts + block dispatch tables ----------------
__global__ void calc_offs(const int* __restrict__ counts, int* __restrict__ offs,
                          int* __restrict__ t1e, int* __restrict__ t1p,
                          int* __restrict__ t2e, int* __restrict__ t2p)
{
  if (threadIdx.x == 0 && blockIdx.x == 0) {
    int a = 0;
#pragma unroll
    for (int e = 0; e < NEXP; ++e) { offs[e] = a; a += counts[e * 32]; }
    offs[NEXP] = a;
    int nb = 0;
    for (int e = 0; e < NEXP; ++e) {
      const int c = counts[e * 32];
      for (int p = 0; p < c; p += 256) { t1e[nb] = e; t1p[nb] = p; ++nb; }
    }
    offs[9] = nb;                     // gemm1 block count (<=71, stride 256)
    nb = 0;
    for (int e = 0; e < NEXP; ++e) {
      const int c = counts[e * 32];
      for (int p = 0; p < c; p += 128) { t2e[nb] = e; t2p[nb] = p; ++nb; }
    }
    offs[10] = nb;                    // gemm2 block count (<=135)
  }
}

// ---------------- weight fp32 [K][N] tile -> bf16 [N][K], unit-swizzled ------
__device__ __forceinline__ void conv_tile(
    const float* __restrict__ se, unsigned short* __restrict__ de,
    int K, int N, int k0, int n0)
{
  __shared__ unsigned short Tb[64][130];
  const int tid = threadIdx.x;
#pragma unroll
  for (int i = 0; i < 8; ++i) {
    const int f = i * 256 + tid;
    const int kl = f >> 5, nq = (f & 31) * 4;
    const float4 v = *(const float4*)(se + (size_t)(k0 + kl) * N + n0 + nq);
    Tb[kl][nq + 0] = f2bf(v.x);
    Tb[kl][nq + 1] = f2bf(v.y);
    Tb[kl][nq + 2] = f2bf(v.z);
    Tb[kl][nq + 3] = f2bf(v.w);
  }
  __syncthreads();
#pragma unroll
  for (int i = 0; i < 4; ++i) {
    const int idx = i * 256 + tid;
    const int n = idx >> 3, up = idx & 7;
    const int kb = (up ^ (n & 7)) * 8;
    union { unsigned short s[8]; uint4 v; } t;
#pragma unroll
    for (int j = 0; j < 8; ++j) t.s[j] = Tb[kb + j][n];
    *(uint4*)(de + ((size_t)(n0 + n) * K + k0 + up * 8)) = t.v;
  }
}

// ---- mega-kernel: weight converts (blocks 0..9215) + gating (9216..11263) ----
__global__ __launch_bounds__(256) void convert_gate(
    const float* __restrict__ w1, const float* __restrict__ w3,
    const float* __restrict__ w2, unsigned short* __restrict__ w1t,
    unsigned short* __restrict__ w3t, unsigned short* __restrict__ w2t,
    const float* __restrict__ x, const float* __restrict__ gw,
    int* __restrict__ counts, int* __restrict__ tok_list,
    float* __restrict__ wt_list, int* __restrict__ slotA,
    int* __restrict__ slotB, unsigned short* __restrict__ xb)
{
  const int g = blockIdx.x;
  if (g < 9216) {
    const int seg = g / 3072, r = g % 3072;
    const int e = r / 384, rr = r % 384;
    if (seg < 2) {
      const float* src = (seg == 0 ? w1 : w3) + (size_t)e * DDIM * HDIM;
      unsigned short* dst = (seg == 0 ? w1t : w3t) + (size_t)e * HDIM * DDIM;
      conv_tile(src, dst, DDIM, HDIM, (rr / 24) * 64, (rr % 24) * 128);
    } else {
      conv_tile(w2 + (size_t)e * HDIM * DDIM, w2t + (size_t)e * DDIM * HDIM,
                HDIM, DDIM, (rr / 8) * 64, (rr % 8) * 128);
    }
    return;
  }
  const int lane = threadIdx.x & 63;
  const int t = (g - 9216) * 4 + (threadIdx.x >> 6);
  const float* xr = x + (size_t)t * DDIM;
  unsigned short* xbr = xb + (size_t)t * DDIM;
  float p[NEXP];
#pragma unroll
  for (int e = 0; e < NEXP; ++e) p[e] = 0.f;
#pragma unroll 4
  for (int i = 0; i < DDIM / 64; ++i) {
    const int d = i * 64 + lane;
    const float xv = xr[d];
    xbr[d] = f2bf(xv);
    const float4 g0 = *(const float4*)(gw + (size_t)d * NEXP);
    const float4 g1 = *(const float4*)(gw + (size_t)d * NEXP + 4);
    p[0] += xv * g0.x; p[1] += xv * g0.y; p[2] += xv * g0.z; p[3] += xv * g0.w;
    p[4] += xv * g1.x; p[5] += xv * g1.y; p[6] += xv * g1.z; p[7] += xv * g1.w;
  }
#pragma unroll
  for (int off = 32; off > 0; off >>= 1) {
#pragma unroll
    for (int e = 0; e < NEXP; ++e) p[e] += __shfl_down(p[e], off);
  }
  if (lane == 0) {
    int i1 = 0; float v1 = p[0];
#pragma unroll
    for (int e = 1; e < NEXP; ++e) if (p[e] > v1) { v1 = p[e]; i1 = e; }
    int i2 = -1; float v2 = -3.4e38f;
#pragma unroll
    for (int e = 0; e < NEXP; ++e) if (e != i1 && p[e] > v2) { v2 = p[e]; i2 = e; }
    const float w0 = 1.f / (1.f + __expf(v2 - v1));
    int q1 = atomicAdd(&counts[i1 * 32], 1);
    tok_list[i1 * T_TOK + q1] = t;
    wt_list[i1 * T_TOK + q1] = w0;
    slotA[t] = i1 * T_TOK + q1;
    int q2 = atomicAdd(&counts[i2 * 32], 1);
    tok_list[i2 * T_TOK + q2] = t;
    wt_list[i2 * T_TOK + q2] = 1.f - w0;
    slotB[t] = i2 * T_TOK + q2;
  }
}

// ---------------- GEMM1: 8-phase counted-vmcnt schedule (T3+T4+T5) ----------
// 256 tok x 128 h-cols, virtual B = [B1;B3] 256 rows. 8 waves split N-only:
// wave wv owns B-rows wv*32..+31 (wv<4 -> w1, wv>=4 -> w3), all 256 token rows.
// K-tile = 64; buf0 even kt, buf1 odd kt; per K-tile 4 quadrant-phases (16 MFMA,
// rows q*64..+63). Half-tile (16KB) staged per phase into DEAD regions only:
//   ph0: b1.B-h1(k1) ph1: b1.B-h2(k1) ph2: b1.A-h2(k1) ph3: b0.A-h1(k2)+vm(4)
//   ph4: b0.A-h2(k2) ph5: b0.B-h1(k2)+vm(6) ph6: b0.B-h2(k2) ph7: b1.A-h1(k3)+vm(2)
// vmcnt never 0 in-loop; raw s_barrier (no implicit drain); setprio around MFMA.
__global__ __launch_bounds__(512, 2) void moe_gemm1(
    const unsigned short* __restrict__ xb, const unsigned short* __restrict__ w1t,
    const unsigned short* __restrict__ w3t, const int* __restrict__ counts,
    const int* __restrict__ offs, const int* __restrict__ t1e,
    const int* __restrict__ t1p, const int* __restrict__ tok_list,
    unsigned short* __restrict__ h_buf)
{
  const int b = blockIdx.y;
  if (b >= offs[9]) return;
  const int e = t1e[b];
  const int p0 = t1p[b];
  const int cnt = counts[e * 32];
  const int n0 = blockIdx.x * 128;
  const int hbase = offs[e];

  // 128 KB: A buf s at s*16384 (ushort), B buf s at 32768 + s*16384.
  __shared__ __align__(16) unsigned short lds[65536];

  const int tid = threadIdx.x;
  const int lane = tid & 63;
  const int wv = tid >> 6;              // 0..7: B-rows wv*32..+31
  const int lr = lane & 15;
  const int lg = lane >> 4;
  const int srow = tid >> 3;            // staging row 0..63
  const int sunit = tid & 7;            // staging 16B unit
  const int aswz = (sunit ^ (srow & 7)) * 16;

  const int* tl = tok_list + e * T_TOK;

  const char* aps[4];                   // [h*2+L]: token-row pointers (+aswz)
#pragma unroll
  for (int h = 0; h < 2; ++h)
#pragma unroll
    for (int L = 0; L < 2; ++L) {
      const int p = p0 + h * 128 + L * 64 + srow;
      const int tok = (p < cnt) ? tl[p] : 0;
      aps[h * 2 + L] = (const char*)(xb + (size_t)tok * DDIM) + aswz;
    }
  const char* bps[4];                   // [h*2+L]: weight-row ptrs (swz baked)
#pragma unroll
  for (int h = 0; h < 2; ++h)
#pragma unroll
    for (int L = 0; L < 2; ++L) {
      const unsigned short* base = h ? w3t : w1t;
      bps[h * 2 + L] =
          (const char*)(base + (size_t)(e * HDIM + n0 + L * 64 + srow) * DDIM)
          + sunit * 16;
    }

  facc acc[4][4][2];                    // [quadrant][m][n]
#pragma unroll
  for (int q = 0; q < 4; ++q)
#pragma unroll
    for (int m = 0; m < 4; ++m)
#pragma unroll
      for (int n = 0; n < 2; ++n)
#pragma unroll
        for (int j = 0; j < 4; ++j) acc[q][m][n][j] = 0.f;

  bfrag bb[2][2];                       // held per K-tile
  bfrag a_[4][2];

#define FENCE asm volatile("" ::: "memory")
#define SB __builtin_amdgcn_s_barrier()
#define SCHB __builtin_amdgcn_sched_barrier(0)
#define VMW(n) asm volatile("s_waitcnt vmcnt(" #n ")" ::: "memory")

#define STGA(s, h, kt)                                                         \
  { gload16(aps[(h) * 2 + 0] + (size_t)(kt) * 128,                             \
            &lds[(s) * 16384 + (h) * 8192 + srow * 64 + sunit * 8]);           \
    gload16(aps[(h) * 2 + 1] + (size_t)(kt) * 128,                             \
            &lds[(s) * 16384 + (h) * 8192 + (64 + srow) * 64 + sunit * 8]); }
#define STGB(s, h, kt)                                                         \
  { gload16(bps[(h) * 2 + 0] + (size_t)(kt) * 128,                             \
            &lds[32768 + (s) * 16384 + (h) * 8192 + srow * 64 + sunit * 8]);   \
    gload16(bps[(h) * 2 + 1] + (size_t)(kt) * 128,                             \
            &lds[32768 + (s) * 16384 + (h) * 8192 + (64 + srow) * 64 + sunit * 8]); }

#define LOADB(s)                                                               \
  _Pragma("unroll") for (int n = 0; n < 2; ++n)                                \
  _Pragma("unroll") for (int ks = 0; ks < 2; ++ks) {                           \
    const int rb = wv * 32 + n * 16 + lr;                                      \
    const int u = (ks * 4 + lg) ^ (lr & 7);                                    \
    bb[n][ks] = *(const bfrag*)&lds[32768 + (s) * 16384 + rb * 64 + u * 8];    \
  }

#define PH(s, q, STG, WAITS)                                                   \
  {                                                                            \
    _Pragma("unroll") for (int m = 0; m < 4; ++m)                              \
    _Pragma("unroll") for (int ks = 0; ks < 2; ++ks) {                         \
      const int r = (q) * 64 + m * 16 + lr;                                    \
      const int u = (ks * 4 + lg) ^ (lr & 7);                                  \
      a_[m][ks] = *(const bfrag*)&lds[(s) * 16384 + r * 64 + u * 8];           \
    }                                                                          \
    STG;                                                                       \
    FENCE; SB; SCHB;                                                           \
    __builtin_amdgcn_s_setprio(1);                                             \
    _Pragma("unroll") for (int ks = 0; ks < 2; ++ks)                           \
    _Pragma("unroll") for (int n = 0; n < 2; ++n)                              \
    _Pragma("unroll") for (int m = 0; m < 4; ++m)                              \
      acc[q][m][n] = __builtin_amdgcn_mfma_f32_16x16x32_bf16(                  \
          a_[m][ks], bb[n][ks], acc[q][m][n], 0, 0, 0);                        \
    __builtin_amdgcn_s_setprio(0);                                             \
    WAITS;                                                                     \
    FENCE; SB; SCHB;                                                           \
  }

  // prologue: buf0 <- kt0 (4 halves), buf1.A-h1 <- kt1; keep last in flight
  STGB(0, 0, 0); STGB(0, 1, 0); STGA(0, 0, 0); STGA(0, 1, 0); STGA(1, 0, 1);
  VMW(2); FENCE; SB; SCHB;

#pragma unroll 1
  for (int t = 0; t < 8; ++t) {
    const int k1 = 2 * t + 1, k2 = 2 * t + 2, k3 = 2 * t + 3;
    LOADB(0);
    PH(0, 0, STGB(1, 0, k1), );
    PH(0, 1, STGB(1, 1, k1), );
    PH(0, 2, STGA(1, 1, k1), );
    PH(0, 3, STGA(0, 0, k2), VMW(4));
    LOADB(1);
    PH(1, 0, STGA(0, 1, k2), );
    PH(1, 1, STGB(0, 0, k2), VMW(6));
    PH(1, 2, STGB(0, 1, k2), );
    PH(1, 3, STGA(1, 0, k3), VMW(2));
  }

  // drain in-flight (garbage kt16/17) stages before LDS reuse
  VMW(0); FENCE;
  __syncthreads();

  // epilogue: 2 passes of 128 rows through LDS [128][256] f32; SwiGLU pair
  // col j (B1, waves 0-3) with col 128+j (B3, waves 4-7); coalesced bf16 out.
  float* Lf = (float*)lds;
#pragma unroll
  for (int P = 0; P < 2; ++P) {
    if (P) __syncthreads();
#pragma unroll
    for (int qq = 0; qq < 2; ++qq)
#pragma unroll
      for (int m = 0; m < 4; ++m)
#pragma unroll
        for (int n = 0; n < 2; ++n)
#pragma unroll
          for (int rg = 0; rg < 4; ++rg)
            Lf[(qq * 64 + m * 16 + lg * 4 + rg) * 256 + wv * 32 + n * 16 + lr] =
                acc[P * 2 + qq][m][n][rg];
    __syncthreads();
#pragma unroll
    for (int it = 0; it < 4; ++it) {
      const int idx = it * 512 + tid;
      const int r = idx >> 4, u = idx & 15;
      const int p = p0 + P * 128 + r;
      if (p < cnt) {
        union { unsigned short s[8]; uint4 v; } o;
#pragma unroll
        for (int j = 0; j < 8; ++j) {
          const float l = Lf[r * 256 + u * 8 + j];
          const float gg = Lf[r * 256 + 128 + u * 8 + j];
          o.s[j] = f2bf(l * gg / (1.f + __expf(-l)));
        }
        *(uint4*)(h_buf + ((size_t)(hbase + p) * HDIM + n0 + u * 8)) = o.v;
      }
    }
  }
#undef PH
#undef LOADB
#undef STGA
#undef STGB
#undef VMW
#undef SCHB
#undef SB
#undef FENCE
}

// ---------------- GEMM2: part[pos] = h @ w2 (no atomics) ----------------
__global__ __launch_bounds__(256, 2) void moe_gemm2(
    const unsigned short* __restrict__ h_buf, const unsigned short* __restrict__ w2t,
    const int* __restrict__ counts, const int* __restrict__ offs,
    const int* __restrict__ t2e, const int* __restrict__ t2p,
    float* __restrict__ part)
{
  const int b = blockIdx.y;
  if (b >= offs[10]) return;
  const int e = t2e[b];
  const int p0 = t2p[b];
  const int cnt = counts[e * 32];
  const int n0 = blockIdx.x * 128;
  const int hbase = offs[e];

  __shared__ __align__(16) unsigned short Ah[128 * 64];
  __shared__ __align__(16) unsigned short Bw[128 * 64];

  const int tid = threadIdx.x;
  const int lane = tid & 63;
  const int wv = tid >> 6;
  const int wm = wv >> 1;
  const int wn = wv & 1;
  const int lr = lane & 15;
  const int lg = lane >> 4;
  const int l8 = lane >> 3;
  const int lu = lane & 7;
  const int aswz = (lu ^ l8) * 16;

  const unsigned short* asrc[4];
#pragma unroll
  for (int i = 0; i < 4; ++i) {
    const int p = p0 + wv * 32 + i * 8 + l8;
    const int hrow = hbase + ((p < cnt) ? p : 0);
    asrc[i] = h_buf + (size_t)hrow * HDIM;
  }
  const unsigned short* bsrc[4];
#pragma unroll
  for (int i = 0; i < 4; ++i) {
    const int n = n0 + wv * 32 + i * 8 + l8;
    bsrc[i] = w2t + (size_t)(e * DDIM + n) * HDIM;
  }

  facc acc[4][4];
#pragma unroll
  for (int m = 0; m < 4; ++m)
#pragma unroll
    for (int n = 0; n < 4; ++n)
#pragma unroll
      for (int q = 0; q < 4; ++q) acc[m][n][q] = 0.f;

#pragma unroll 1
  for (int k0 = 0; k0 < HDIM; k0 += 64) {
#pragma unroll
    for (int i = 0; i < 4; ++i)
      gload16((const char*)asrc[i] + k0 * 2 + aswz, &Ah[(wv * 4 + i) * 512]);
#pragma unroll
    for (int i = 0; i < 4; ++i)
      gload16((const char*)bsrc[i] + k0 * 2 + lu * 16, &Bw[(wv * 4 + i) * 512]);
    __syncthreads();
#pragma unroll
    for (int ks = 0; ks < 2; ++ks) {
      bfrag a[4];
#pragma unroll
      for (int m = 0; m < 4; ++m) {
        const int r = wm * 64 + m * 16 + lr;
        const int u = (ks * 4 + lg) ^ (r & 7);
        a[m] = *(const bfrag*)&Ah[r * 64 + u * 8];
      }
#pragma unroll
      for (int n = 0; n < 4; ++n) {
        const int rb = wn * 64 + n * 16 + lr;
        const int u = (ks * 4 + lg) ^ (rb & 7);
        const bfrag bbv = *(const bfrag*)&Bw[rb * 64 + u * 8];
#pragma unroll
        for (int m = 0; m < 4; ++m)
          acc[m][n] = __builtin_amdgcn_mfma_f32_16x16x32_bf16(a[m], bbv, acc[m][n], 0, 0, 0);
      }
    }
    __syncthreads();
  }

#pragma unroll
  for (int m = 0; m < 4; ++m)
#pragma unroll
    for (int q = 0; q < 4; ++q) {
      const int p = p0 + wm * 64 + m * 16 + lg * 4 + q;
      if (p < cnt) {
        float* dst = part + (size_t)(hbase + p) * DDIM + n0 + wn * 64 + lr;
#pragma unroll
        for (int n = 0; n < 4; ++n)
          dst[n * 16] = acc[m][n][q];
      }
    }
}

// ---------------- combine: out[t] = wA*part[posA] + wB*part[posB] ----------------
__global__ __launch_bounds__(256) void combine_out(
    const float* __restrict__ part, const int* __restrict__ slotA,
    const int* __restrict__ slotB, const float* __restrict__ wt_list,
    const int* __restrict__ offs, float* __restrict__ out)
{
  const int t = blockIdx.x;
  const int sA = slotA[t], sB = slotB[t];
  const float wA = wt_list[sA], wB = wt_list[sB];
  const int pA = offs[sA >> 13] + (sA & (T_TOK - 1));
  const int pB = offs[sB >> 13] + (sB & (T_TOK - 1));
  const float* ra = part + (size_t)pA * DDIM;
  const float* rb = part + (size_t)pB * DDIM;
  float* o = out + (size_t)t * DDIM;
  const int i = threadIdx.x * 4;
  const float4 a = *(const float4*)(ra + i);
  const float4 b = *(const float4*)(rb + i);
  float4 r;
  r.x = wA * a.x + wB * b.x;
  r.y = wA * a.y + wB * b.y;
  r.z = wA * a.z + wB * b.z;
  r.w = wA * a.w + wB * b.w;
  *(float4*)(o + i) = r;
}

// ================= fallback path (previous verified kernels) =================
__global__ __launch_bounds__(64) void gate_topk_fb(
    const float* __restrict__ x, const float* __restrict__ gw,
    int* __restrict__ counts, int* __restrict__ tok_list,
    float* __restrict__ wt_list)
{
  const int t = blockIdx.x;
  const int lane = threadIdx.x;
  const float* xr = x + (size_t)t * DDIM;
  float p[NEXP];
#pragma unroll
  for (int e = 0; e < NEXP; ++e) p[e] = 0.f;
#pragma unroll 4
  for (int i = 0; i < DDIM / 64; ++i) {
    const int d = i * 64 + lane;
    const float xv = xr[d];
    const float4 g0 = *(const float4*)(gw + (size_t)d * NEXP);
    const float4 g1 = *(const float4*)(gw + (size_t)d * NEXP + 4);
    p[0] += xv * g0.x; p[1] += xv * g0.y; p[2] += xv * g0.z; p[3] += xv * g0.w;
    p[4] += xv * g1.x; p[5] += xv * g1.y; p[6] += xv * g1.z; p[7] += xv * g1.w;
  }
#pragma unroll
  for (int off = 32; off > 0; off >>= 1) {
#pragma unroll
    for (int e = 0; e < NEXP; ++e) p[e] += __shfl_down(p[e], off);
  }
  if (lane == 0) {
    int i1 = 0; float v1 = p[0];
#pragma unroll
    for (int e = 1; e < NEXP; ++e) if (p[e] > v1) { v1 = p[e]; i1 = e; }
    int i2 = -1; float v2 = -3.4e38f;
#pragma unroll
    for (int e = 0; e < NEXP; ++e) if (e != i1 && p[e] > v2) { v2 = p[e]; i2 = e; }
    const float w0 = 1.f / (1.f + __expf(v2 - v1));
    int q1 = atomicAdd(&counts[i1 * 32], 1);
    tok_list[i1 * T_TOK + q1] = t;
    wt_list[i1 * T_TOK + q1] = w0;
    int q2 = atomicAdd(&counts[i2 * 32], 1);
    tok_list[i2 * T_TOK + q2] = t;
    wt_list[i2 * T_TOK + q2] = 1.f - w0;
  }
}

__global__ __launch_bounds__(256) void moe_gemm1_fb(
    const float* __restrict__ x, const float* __restrict__ w1,
    const float* __restrict__ w3, const int* __restrict__ counts,
    const int* __restrict__ tok_list, unsigned short* __restrict__ h_buf,
    int e)
{
  const int cnt = counts[e * 32];
  const int p0 = blockIdx.y * 64;
  if (p0 >= cnt) return;
  const int n0 = blockIdx.x * 64;

  __shared__ unsigned short As[64][40];
  __shared__ unsigned short B1s[64][40];
  __shared__ unsigned short B3s[64][40];

  const int tid = threadIdx.x;
  const int lane = tid & 63;
  const int wv = tid >> 6;

  const float* w1e = w1 + (size_t)e * DDIM * HDIM;
  const float* w3e = w3 + (size_t)e * DDIM * HDIM;
  const int* tl = tok_list + e * T_TOK;

  const int arow = tid >> 2;
  const int akseg = (tid & 3) * 8;
  int tok = -1;
  if (p0 + arow < cnt) tok = tl[p0 + arow];

  const int bk = tid >> 3;
  const int bn4 = (tid & 7) * 4;

  facc acc1[4], acc3[4];
#pragma unroll
  for (int i = 0; i < 4; ++i)
#pragma unroll
    for (int j = 0; j < 4; ++j) { acc1[i][j] = 0.f; acc3[i][j] = 0.f; }

  const int mrow = wv * 16 + (lane & 15);
  const int kq = (lane >> 4) * 8;

  for (int k0 = 0; k0 < DDIM; k0 += 32) {
    {
      union { unsigned short s[8]; uint4 v; } tmp;
      if (tok >= 0) {
        const float* src = x + (size_t)tok * DDIM + k0 + akseg;
        const float4 f0 = *(const float4*)(src);
        const float4 f1 = *(const float4*)(src + 4);
        tmp.s[0]=f2bf(f0.x); tmp.s[1]=f2bf(f0.y); tmp.s[2]=f2bf(f0.z); tmp.s[3]=f2bf(f0.w);
        tmp.s[4]=f2bf(f1.x); tmp.s[5]=f2bf(f1.y); tmp.s[6]=f2bf(f1.z); tmp.s[7]=f2bf(f1.w);
      } else {
        tmp.v = make_uint4(0u, 0u, 0u, 0u);
      }
      *(uint4*)&As[arow][akseg] = tmp.v;
    }
#pragma unroll
    for (int pass = 0; pass < 2; ++pass) {
      const int n = bn4 + pass * 32;
      const float4 f1v = *(const float4*)(w1e + (size_t)(k0 + bk) * HDIM + n0 + n);
      B1s[n + 0][bk] = f2bf(f1v.x);
      B1s[n + 1][bk] = f2bf(f1v.y);
      B1s[n + 2][bk] = f2bf(f1v.z);
      B1s[n + 3][bk] = f2bf(f1v.w);
      const float4 f3v = *(const float4*)(w3e + (size_t)(k0 + bk) * HDIM + n0 + n);
      B3s[n + 0][bk] = f2bf(f3v.x);
      B3s[n + 1][bk] = f2bf(f3v.y);
      B3s[n + 2][bk] = f2bf(f3v.z);
      B3s[n + 3][bk] = f2bf(f3v.w);
    }
    __syncthreads();
    const bfrag a = *(const bfrag*)&As[mrow][kq];
#pragma unroll
    for (int nt = 0; nt < 4; ++nt) {
      const bfrag b1 = *(const bfrag*)&B1s[nt * 16 + (lane & 15)][kq];
      acc1[nt] = __builtin_amdgcn_mfma_f32_16x16x32_bf16(a, b1, acc1[nt], 0, 0, 0);
      const bfrag b3 = *(const bfrag*)&B3s[nt * 16 + (lane & 15)][kq];
      acc3[nt] = __builtin_amdgcn_mfma_f32_16x16x32_bf16(a, b3, acc3[nt], 0, 0, 0);
    }
    __syncthreads();
  }
  const int rbase = p0 + wv * 16 + ((lane >> 4) * 4);
  const int cbase = n0 + (lane & 15);
#pragma unroll
  for (int r = 0; r < 4; ++r) {
    const int p = rbase + r;
    if (p < cnt) {
      unsigned short* dst = h_buf + (size_t)p * HDIM + cbase;
#pragma unroll
      for (int nt = 0; nt < 4; ++nt) {
        const float a1 = acc1[nt][r];
        const float a3 = acc3[nt][r];
        const float hv = a1 * a3 / (1.f + __expf(-a1));
        dst[nt * 16] = f2bf(hv);
      }
    }
  }
}

__global__ __launch_bounds__(256) void moe_gemm2_fb(
    const unsigned short* __restrict__ h_buf, const float* __restrict__ w2,
    const int* __restrict__ counts, const int* __restrict__ tok_list,
    const float* __restrict__ wt_list, float* __restrict__ out, int e)
{
  const int cnt = counts[e * 32];
  const int p0 = blockIdx.y * 64;
  if (p0 >= cnt) return;
  const int n0 = blockIdx.x * 64;

  __shared__ unsigned short As[64][40];
  __shared__ unsigned short Bs[64][40];

  const int tid = threadIdx.x;
  const int lane = tid & 63;
  const int wv = tid >> 6;

  const float* w2e = w2 + (size_t)e * HDIM * DDIM;
  const int* tl = tok_list + e * T_TOK;
  const float* wl = wt_list + e * T_TOK;

  const int arow = tid >> 2;
  const int akseg = (tid & 3) * 8;
  const bool avalid = (p0 + arow < cnt);

  const int bk = tid >> 3;
  const int bn4 = (tid & 7) * 4;

  facc acc[4];
#pragma unroll
  for (int i = 0; i < 4; ++i)
#pragma unroll
    for (int j = 0; j < 4; ++j) acc[i][j] = 0.f;

  const int mrow = wv * 16 + (lane & 15);
  const int kq = (lane >> 4) * 8;

  for (int k0 = 0; k0 < HDIM; k0 += 32) {
    if (avalid) {
      *(uint4*)&As[arow][akseg] =
          *(const uint4*)(h_buf + (size_t)(p0 + arow) * HDIM + k0 + akseg);
    } else {
      *(uint4*)&As[arow][akseg] = make_uint4(0u, 0u, 0u, 0u);
    }
#pragma unroll
    for (int pass = 0; pass < 2; ++pass) {
      const int n = bn4 + pass * 32;
      const float4 f = *(const float4*)(w2e + (size_t)(k0 + bk) * DDIM + n0 + n);
      Bs[n + 0][bk] = f2bf(f.x);
      Bs[n + 1][bk] = f2bf(f.y);
      Bs[n + 2][bk] = f2bf(f.z);
      Bs[n + 3][bk] = f2bf(f.w);
    }
    __syncthreads();
    const bfrag a = *(const bfrag*)&As[mrow][kq];
#pragma unroll
    for (int nt = 0; nt < 4; ++nt) {
      const bfrag b = *(const bfrag*)&Bs[nt * 16 + (lane & 15)][kq];
      acc[nt] = __builtin_amdgcn_mfma_f32_16x16x32_bf16(a, b, acc[nt], 0, 0, 0);
    }
    __syncthreads();
  }
  const int rbase = p0 + wv * 16 + ((lane >> 4) * 4);
  const int cbase = n0 + (lane & 15);
#pragma unroll
  for (int r = 0; r < 4; ++r) {
    const int p = rbase + r;
    if (p < cnt) {
      const int tok = tl[p];
      const float wt = wl[p];
      float* dst = out + (size_t)tok * DDIM + cbase;
#pragma unroll
      for (int nt = 0; nt < 4; ++nt) {
        atomicAdd(dst + nt * 16, acc[nt][r] * wt);
      }
    }
  }
}

__global__ void ws_too_small(float* out, int n) {
  int i = blockIdx.x * 256 + threadIdx.x;
  if (i < n) out[i] = 1.0e6f;
}

extern "C" void kernel_launch(void* const* d_in, const int* in_sizes, int n_in,
                              void* d_out, int out_size, void* d_ws, size_t ws_size,
                              hipStream_t stream) {
  const float* x  = (const float*)d_in[0];
  const float* gw = (const float*)d_in[1];
  const float* w1 = (const float*)d_in[2];
  const float* w3 = (const float*)d_in[3];
  const float* w2 = (const float*)d_in[4];
  float* out = (float*)d_out;

  const size_t off_tok = 5120;
  const size_t off_wt  = off_tok + (size_t)NEXP * T_TOK * 4;
  const size_t off_sA  = off_wt + (size_t)NEXP * T_TOK * 4;
  const size_t off_sB  = off_sA + (size_t)T_TOK * 4;
  const size_t off_xb  = off_sB + (size_t)T_TOK * 4;
  const size_t off_w1t = off_xb + (size_t)T_TOK * DDIM * 2;
  const size_t off_w3t = off_w1t + (size_t)NEXP * DDIM * HDIM * 2;
  const size_t off_w2t = off_w3t + (size_t)NEXP * DDIM * HDIM * 2;
  const size_t off_h   = off_w2t + (size_t)NEXP * HDIM * DDIM * 2;
  const size_t need    = off_h + (size_t)(2 * T_TOK) * HDIM * 2;
  const size_t off_part = off_w1t;   // aliases dead w1t/w3t after gemm1

  if (ws_size >= need) {
    int* counts = (int*)d_ws;
    int* offs = (int*)((char*)d_ws + 1024);
    int* t1e = (int*)((char*)d_ws + 2048);
    int* t1p = (int*)((char*)d_ws + 2688);
    int* t2e = (int*)((char*)d_ws + 3328);
    int* t2p = (int*)((char*)d_ws + 3968);
    int* tok_list = (int*)((char*)d_ws + off_tok);
    float* wt_list = (float*)((char*)d_ws + off_wt);
    int* slotA = (int*)((char*)d_ws + off_sA);
    int* slotB = (int*)((char*)d_ws + off_sB);
    unsigned short* xb  = (unsigned short*)((char*)d_ws + off_xb);
    unsigned short* w1t = (unsigned short*)((char*)d_ws + off_w1t);
    unsigned short* w3t = (unsigned short*)((char*)d_ws + off_w3t);
    unsigned short* w2t = (unsigned short*)((char*)d_ws + off_w2t);
    unsigned short* h_buf = (unsigned short*)((char*)d_ws + off_h);
    float* part = (float*)((char*)d_ws + off_part);

    hipMemsetAsync(counts, 0, 1024, stream);

    convert_gate<<<9216 + T_TOK / 4, 256, 0, stream>>>(
        w1, w3, w2, w1t, w3t, w2t, x, gw, counts, tok_list, wt_list,
        slotA, slotB, xb);
    calc_offs<<<1, 1, 0, stream>>>(counts, offs, t1e, t1p, t2e, t2p);
    moe_gemm1<<<dim3(HDIM / 128, 72), 512, 0, stream>>>(
        xb, w1t, w3t, counts, offs, t1e, t1p, tok_list, h_buf);
    moe_gemm2<<<dim3(DDIM / 128, 144), 256, 0, stream>>>(
        h_buf, w2t, counts, offs, t2e, t2p, part);
    combine_out<<<T_TOK, 256, 0, stream>>>(part, slotA, slotB, wt_list, offs, out);
    return;
  }

  const size_t fb_off_tok = 1024;
  const size_t fb_off_wt  = fb_off_tok + (size_t)NEXP * T_TOK * 4;
  const size_t fb_off_h   = fb_off_wt + (size_t)NEXP * T_TOK * 4;
  const size_t fb_need    = fb_off_h + (size_t)T_TOK * HDIM * 2;
  if (ws_size < fb_need) {
    ws_too_small<<<(out_size + 255) / 256, 256, 0, stream>>>(out, out_size);
    return;
  }
  int* counts = (int*)d_ws;
  int* tok_list = (int*)((char*)d_ws + fb_off_tok);
  float* wt_list = (float*)((char*)d_ws + fb_off_wt);
  unsigned short* h_buf = (unsigned short*)((char*)d_ws + fb_off_h);

  hipMemsetAsync(counts, 0, 1024, stream);
  hipMemsetAsync(out, 0, (size_t)out_size * sizeof(float), stream);

  gate_topk_fb<<<T_TOK, 64, 0, stream>>>(x, gw, counts, tok_list, wt_list);
  for (int e = 0; e < NEXP; ++e) {
    moe_gemm1_fb<<<dim3(HDIM / 64, T_TOK / 64), 256, 0, stream>>>(
        x, w1, w3, counts, tok_list, h_buf, e);
    moe_gemm2_fb<<<dim3(DDIM / 64, T_TOK / 64), 256, 0, stream>>>(
        h_buf, w2, counts, tok_list, wt_list, out, e);
  }
}